// Round 9
// baseline (294.490 us; speedup 1.0000x reference)
//
#include <hip/hip_runtime.h>

// Problem constants
#define B_SZ 16
#define CIN  512
#define LIN  1024
#define LP   1022      // L - K + 1
#define HEADS 8
#define DH    64

typedef __attribute__((ext_vector_type(8))) short bf16x8;
typedef __attribute__((ext_vector_type(4))) float f32x4;
typedef __attribute__((ext_vector_type(16))) float f32x16;

__device__ inline unsigned short f2bf(float f) {
    union { float f; unsigned int u; } c; c.f = f;
    unsigned int r = c.u + 0x7FFF + ((c.u >> 16) & 1);   // RNE
    return (unsigned short)(r >> 16);
}

// async global->LDS DMA, 16B per lane, LDS dst = wave-uniform base + lane*16
__device__ __forceinline__ void gl_lds16(const unsigned short* g, unsigned short* l) {
    __builtin_amdgcn_global_load_lds((const __attribute__((address_space(1))) void*)g,
                                     (__attribute__((address_space(3))) void*)l, 16, 0, 0);
}

// XOR swizzle on 16B granules: involution, preserves 8-granule blocks,
// spreads 16 consecutive rows across all 8 bank groups (2-way = free).
#define SWZ(G) ((G) ^ (((G) >> 3) & 7))

// ---------------------------------------------------------------------------
// xb cvt: x fp32 [b][512 i][1024 l] -> xb bf16 [b][1024 l][512 i]
// ---------------------------------------------------------------------------
__global__ __launch_bounds__(256) void xb_cvt_kernel(const float* __restrict__ x,
                                                     unsigned short* __restrict__ xb) {
    __shared__ float sm[64][68];
    const int t  = threadIdx.x;
    const int l0 = blockIdx.x * 64;
    const int i0 = blockIdx.y * 64;
    const int b  = blockIdx.z;
    const float* S = x + ((size_t)b * CIN + i0) * LIN;

    #pragma unroll
    for (int rr = 0; rr < 4; rr++) {
        int idx = rr * 1024 + t * 4;
        int ii = idx >> 6, lj = idx & 63;
        *(float4*)&sm[ii][lj] = *(const float4*)(S + (size_t)ii * LIN + l0 + lj);
    }
    __syncthreads();

    #pragma unroll
    for (int rr = 0; rr < 4; rr++) {
        int idx = rr * 1024 + t * 4;
        int l = idx >> 6, dj = idx & 63;
        ushort4 h;
        h.x = f2bf(sm[dj + 0][l]);
        h.y = f2bf(sm[dj + 1][l]);
        h.z = f2bf(sm[dj + 2][l]);
        h.w = f2bf(sm[dj + 3][l]);
        *(ushort4*)(xb + ((size_t)b * 1024 + l0 + l) * 512 + i0 + dj) = h;
    }
}

// ---------------------------------------------------------------------------
// wb cvt: w_c[o][i][kk] fp32 -> wb bf16 [kk][O=c*512+o][i]
// ---------------------------------------------------------------------------
__global__ __launch_bounds__(256) void wb_cvt_kernel(const float* __restrict__ w0,
                                                     const float* __restrict__ w1,
                                                     const float* __restrict__ w2,
                                                     unsigned short* __restrict__ wb) {
    const int kk = blockIdx.y;
    int flat = blockIdx.x * 256 + threadIdx.x;
    int i  = flat & 511;
    int oG = flat >> 9;
    int c  = oG >> 9, o = oG & 511;
    const float* w = (c == 0) ? w0 : (c == 1) ? w1 : w2;
    wb[(size_t)kk * 786432 + flat] = f2bf(w[o * 1536 + i * 3 + kk]);
}

// ---------------------------------------------------------------------------
// Fused 3-conv bf16 MFMA GEMM with global_load_lds staging + XOR-swizzled LDS.
// Round-0/5 structure (median 93 us, the m97 plateau). DPP tap-dedup (round 8)
// REVERTED: it zeroed bank conflicts and raised VALUBusy 19->32 with no speed
// change — conv is structure/latency-bound, not DS-pipe-bound. Frozen.
// ---------------------------------------------------------------------------
__global__ __launch_bounds__(256) void conv_mfma_kernel(
        const unsigned short* __restrict__ xb,   // [16][1024][512]
        const unsigned short* __restrict__ wb,   // [3][1536][512]
        const float* __restrict__ b0, const float* __restrict__ b1,
        const float* __restrict__ b2,
        unsigned short* __restrict__ Qt, unsigned short* __restrict__ Kt,
        unsigned short* __restrict__ Vt, float qscale) {
    __shared__ unsigned short smem[16896];       // staging 16512 sh | vt 16896 sh
    unsigned short* xs = smem;                   // [132][32]
    unsigned short* ws = smem + 4224;            // [384][32]

    const int t    = threadIdx.x;
    const int wave = t >> 6;
    const int lane = t & 63;
    const int col  = lane & 15;
    const int quad = lane >> 4;
    const int wh   = wave >> 1;                  // o half
    const int wn   = wave & 1;                   // l half
    const int l0   = blockIdx.x * 128;
    const int o0   = blockIdx.y * 128;
    const int b    = blockIdx.z;

    f32x4 acc[4][4];
    #pragma unroll
    for (int i = 0; i < 4; i++)
        #pragma unroll
        for (int j = 0; j < 4; j++) acc[i][j] = (f32x4){0.f, 0.f, 0.f, 0.f};

    const unsigned short* xrow = xb + (size_t)b * 1024 * 512;

    for (int ic = 0; ic < 512; ic += 32) {
        __syncthreads();   // previous chunk's compute done before overwrite

        // ---- W DMA: 24 instrs (16 rows each), this wave does 6 ----
        #pragma unroll
        for (int j = 0; j < 6; j++) {
            int instr = wave * 6 + j;
            int Gg = SWZ(instr * 64 + lane);
            int p = Gg >> 2, q = Gg & 3;
            int kk = p >> 7, orow = p & 127;
            gl_lds16(wb + ((size_t)(kk * 1536 + o0 + orow)) * 512 + ic + q * 8,
                     ws + instr * 512);
        }
        // ---- X DMA: 8 instrs for rows 0..127, this wave does 2 ----
        #pragma unroll
        for (int j = 0; j < 2; j++) {
            int instr = wave * 2 + j;
            int Gg = SWZ(instr * 64 + lane);
            int p = Gg >> 2, q = Gg & 3;
            gl_lds16(xrow + (size_t)(l0 + p) * 512 + ic + q * 8,
                     xs + instr * 512);
        }
        // ---- halo rows 128,129 (checked, zero-fill OOB) ----
        if (t < 8) {
            int row = 128 + (t >> 2), sg = t & 3;
            int gl = l0 + row;
            bf16x8 v = (bf16x8){0, 0, 0, 0, 0, 0, 0, 0};
            if (gl < 1024) v = *(const bf16x8*)(xrow + (size_t)gl * 512 + ic + sg * 8);
            *(bf16x8*)&xs[SWZ(512 + t) * 8] = v;
        }
        __syncthreads();   // drains vmcnt (DMA) + lgkmcnt (halo)

        #pragma unroll
        for (int kk = 0; kk < 3; kk++) {
            bf16x8 af[4], bfr[4];
            #pragma unroll
            for (int ms = 0; ms < 4; ms++) {
                int G = ((kk * 128 + wh * 64 + ms * 16 + col) << 2) | quad;
                af[ms] = *(const bf16x8*)&ws[SWZ(G) * 8];
            }
            #pragma unroll
            for (int ns = 0; ns < 4; ns++) {
                int G = ((wn * 64 + ns * 16 + col + kk) << 2) | quad;
                bfr[ns] = *(const bf16x8*)&xs[SWZ(G) * 8];
            }
            #pragma unroll
            for (int ms = 0; ms < 4; ms++)
                #pragma unroll
                for (int ns = 0; ns < 4; ns++)
                    acc[ms][ns] = __builtin_amdgcn_mfma_f32_16x16x32_bf16(af[ms], bfr[ns], acc[ms][ns], 0, 0, 0);
        }
    }

    const int c = blockIdx.y >> 2;               // which conv (uniform per block)

    if (c < 2) {
        // ---- Q/K epilogue: direct bf16 stores to [bh][l][d] ----
        unsigned short* dst = (c == 0) ? Qt : Kt;
        const float* bias   = (c == 0) ? b0 : b1;
        const float sc      = (c == 0) ? qscale : 1.0f;
        const int h = (((o0 & 511) + wh * 64) >> 6) & 7;
        unsigned short* base = dst + (size_t)(b * 8 + h) * 65536;
        #pragma unroll
        for (int ms = 0; ms < 4; ms++) {
            int ob = (o0 & 511) + wh * 64 + ms * 16 + quad * 4;
            float bv[4];
            #pragma unroll
            for (int r = 0; r < 4; r++) bv[r] = bias[ob + r];
            int d0 = ms * 16 + quad * 4;
            #pragma unroll
            for (int ns = 0; ns < 4; ns++) {
                int l = l0 + wn * 64 + ns * 16 + col;
                ushort4 hv;
                hv.x = f2bf((acc[ms][ns][0] + bv[0]) * sc);
                hv.y = f2bf((acc[ms][ns][1] + bv[1]) * sc);
                hv.z = f2bf((acc[ms][ns][2] + bv[2]) * sc);
                hv.w = f2bf((acc[ms][ns][3] + bv[3]) * sc);
                *(ushort4*)(base + (size_t)l * 64 + d0) = hv;
            }
        }
    } else {
        // ---- V epilogue: LDS transpose then coalesced rows to [bh][d][1024] ----
        __syncthreads();
        unsigned short* vt = smem;               // [128][132]
        #pragma unroll
        for (int ms = 0; ms < 4; ms++) {
            int ob = (o0 & 511) + wh * 64 + ms * 16 + quad * 4;
            #pragma unroll
            for (int ns = 0; ns < 4; ns++) {
                int lc = wn * 64 + ns * 16 + col;
                #pragma unroll
                for (int r = 0; r < 4; r++)
                    vt[(wh * 64 + ms * 16 + quad * 4 + r) * 132 + lc] =
                        f2bf(acc[ms][ns][r] + b2[ob + r]);
            }
        }
        __syncthreads();
        #pragma unroll
        for (int it = 0; it < 8; it++) {
            int flat = it * 2048 + t * 8;
            int row = flat >> 7, colx = flat & 127;
            bf16x8 v = *(const bf16x8*)&vt[row * 132 + colx];
            int og = (o0 & 511) + row;
            int h = og >> 6, d = og & 63;
            *(bf16x8*)(Vt + ((size_t)(b * 8 + h) * 64 + d) * 1024 + l0 + colx) = v;
        }
    }
}

// ---------------------------------------------------------------------------
// Flash attention, 32x32x16 MFMA, no-max softmax (p = 2^s, log2e in Q).
// Swapped QK (A=K, B=Q); P fully in-register (round-6 structure).
//
// Round 9: NO LDS staging at all. K/V per bh (256KB) is L2-resident (XCD
// swizzle -> 16 bh x 256KB = 4MB = one XCD's L2); each wave global-loads its
// fragments directly (same bytes the DMA+ds_read pair produced, full row
// utilization). Deletes all barriers/vmcnt drains — waves fully independent,
// compiler pipelines loads across tiles (Common-mistake #7 / m169 remedy).
// Pack exchange: v_permlane32_swap_b32 (x'={x.lo,y.lo}, y'={x.hi,y.hi})
// replaces 4 shfl_xor + 4 selects per pair (m255: 1.20x vs ds_bpermute).
// ---------------------------------------------------------------------------
__global__ __launch_bounds__(256, 3) void attn_kernel(
        const unsigned short* __restrict__ Qt,
        const unsigned short* __restrict__ Kt,
        const unsigned short* __restrict__ Vt,
        float* __restrict__ out) {
    const int t    = threadIdx.x;
    const int wave = t >> 6;
    const int lane = t & 63;
    const int col5 = lane & 31;
    const int hi   = lane >> 5;

    // XCD-grouping swizzle (bijective over the 1024-block grid): each XCD
    // gets 16 bh x 8 qb, so K/V panels are reused within one L2.
    const int lin = blockIdx.y * 8 + blockIdx.x; // 0..1023
    const int xcd = lin & 7;
    const int idx = lin >> 3;                    // 0..127
    const int qb  = idx >> 4;                    // 0..7
    const int bh  = xcd * 16 + (idx & 15);       // 0..127

    const size_t base64 = (size_t)bh * 65536;
    const int q0 = qb * 128 + wave * 32;

    // Q B-frags: bq[s] = Q[q0+col5][s*16 + hi*8 + e]
    bf16x8 bq[4];
    {
        const unsigned short* qrow = Qt + base64 + (size_t)(q0 + col5) * 64 + hi * 8;
        #pragma unroll
        for (int s = 0; s < 4; s++) bq[s] = *(const bf16x8*)(qrow + s * 16);
    }

    f32x16 o0, o1;                               // O[d=col-rows], d-blocks 0/1
    #pragma unroll
    for (int i = 0; i < 16; i++) { o0[i] = 0.f; o1[i] = 0.f; }
    float osum = 0.f;

    // direct-load base pointers (L2-resident)
    const unsigned short* kp0 = Kt + base64 + (size_t)col5 * 64 + hi * 8;   // + krow*64
    const unsigned short* vp0 = Vt + base64 + (size_t)col5 * 1024 + hi * 8; // + d-blk*32*1024 + keyoff

    for (int kt = 0; kt < 16; kt++) {
        #pragma unroll
        for (int kb = 0; kb < 2; kb++) {
            const int k0 = kt * 64 + kb * 32;    // first key of this 32-block
            // ---- K frags: K[k0+col5][s*16 + hi*8 ..] ----
            const unsigned short* kp = kp0 + (size_t)k0 * 64;
            bf16x8 ak[4];
            #pragma unroll
            for (int s = 0; s < 4; s++) ak[s] = *(const bf16x8*)(kp + s * 16);
            // ---- V frags: V[db*32+col5][k0 + (s*2+hi)*8 ..] ----
            bf16x8 av[2][2];
            #pragma unroll
            for (int db = 0; db < 2; db++)
                #pragma unroll
                for (int s = 0; s < 2; s++)
                    av[db][s] = *(const bf16x8*)(vp0 + (size_t)db * 32768 + k0 + s * 16);

            // ---- S^T = K Q^T over d (4 chained K=16 steps) ----
            f32x16 p;
            #pragma unroll
            for (int i = 0; i < 16; i++) p[i] = 0.f;
            __builtin_amdgcn_s_setprio(1);
            #pragma unroll
            for (int s = 0; s < 4; s++)
                p = __builtin_amdgcn_mfma_f32_32x32x16_bf16(ak[s], bq[s], p, 0, 0, 0);
            __builtin_amdgcn_s_setprio(0);

            // ---- p = 2^s in-register; rowsum locally ----
            float e[16];
            #pragma unroll
            for (int r = 0; r < 16; r++) e[r] = exp2f(p[r]);
            if (kt == 15 && kb == 1 && hi == 1) { e[14] = 0.f; e[15] = 0.f; }  // keys 1022,1023
            #pragma unroll
            for (int r = 0; r < 16; r++) osum += e[r];

            // ---- build PV B-frags: cvt_pk + permlane32_swap cross-half ----
            bf16x8 bp[2];
            #pragma unroll
            for (int s = 0; s < 2; s++) {
                unsigned int a, b_, c, d;
                asm("v_cvt_pk_bf16_f32 %0, %1, %2" : "=v"(a)  : "v"(e[s*8+0]), "v"(e[s*8+1]));
                asm("v_cvt_pk_bf16_f32 %0, %1, %2" : "=v"(b_) : "v"(e[s*8+2]), "v"(e[s*8+3]));
                asm("v_cvt_pk_bf16_f32 %0, %1, %2" : "=v"(c)  : "v"(e[s*8+4]), "v"(e[s*8+5]));
                asm("v_cvt_pk_bf16_f32 %0, %1, %2" : "=v"(d)  : "v"(e[s*8+6]), "v"(e[s*8+7]));
                // after swap: a={a.lo,c.lo} (word0), c={a.hi,c.hi} (word2)
                asm("v_permlane32_swap_b32 %0, %1" : "+v"(a), "+v"(c));
                asm("v_permlane32_swap_b32 %0, %1" : "+v"(b_), "+v"(d));
                union { unsigned int u[4]; bf16x8 v; } pk;
                pk.u[0] = a;
                pk.u[1] = b_;
                pk.u[2] = c;
                pk.u[3] = d;
                bp[s] = pk.v;
            }

            // ---- O += V P ----
            __builtin_amdgcn_s_setprio(1);
            #pragma unroll
            for (int s = 0; s < 2; s++) {
                o0 = __builtin_amdgcn_mfma_f32_32x32x16_bf16(av[0][s], bp[s], o0, 0, 0, 0);
                o1 = __builtin_amdgcn_mfma_f32_32x32x16_bf16(av[1][s], bp[s], o1, 0, 0, 0);
            }
            __builtin_amdgcn_s_setprio(0);
        }
    }

    // ---- epilogue: rowsum cross-half combine, divide, store ----
    float osum_t = osum + __shfl_xor(osum, 32);
    float inv = 1.0f / osum_t;
    int q = q0 + col5;
    if (q < LP) {
        #pragma unroll
        for (int r = 0; r < 16; r++) {
            int d0 = (r & 3) + 8 * (r >> 2) + 4 * hi;
            out[((size_t)(bh * 64 + d0)) * LP + q]      = o0[r] * inv;
            out[((size_t)(bh * 64 + d0 + 32)) * LP + q] = o1[r] * inv;
        }
    }
}

// ---------------------------------------------------------------------------
extern "C" void kernel_launch(void* const* d_in, const int* in_sizes, int n_in,
                              void* d_out, int out_size, void* d_ws, size_t ws_size,
                              hipStream_t stream) {
    const float* x  = (const float*)d_in[0];
    const float* w0 = (const float*)d_in[1];
    const float* b0 = (const float*)d_in[2];
    const float* w1 = (const float*)d_in[3];
    const float* b1 = (const float*)d_in[4];
    const float* w2 = (const float*)d_in[5];
    const float* b2 = (const float*)d_in[6];
    float* out = (float*)d_out;

    // workspace (ushort units): xb 8388608 | wb 2359296 | Qt/Kt/Vt 8388608 each
    unsigned short* xbp = (unsigned short*)d_ws;
    unsigned short* wbp = xbp + 8388608;
    unsigned short* Qt  = wbp + 2359296;
    unsigned short* Kt  = Qt + 8388608;
    unsigned short* Vt  = Kt + 8388608;

    // 1/sqrt(512) * log2(e): softmax computed as 2^s
    const float scale = 0.06375870864f;

    xb_cvt_kernel<<<dim3(16, 8, 16), 256, 0, stream>>>(x, xbp);
    wb_cvt_kernel<<<dim3(3072, 3), 256, 0, stream>>>(w0, w1, w2, wbp);
    conv_mfma_kernel<<<dim3(8, 12, 16), 256, 0, stream>>>(xbp, wbp, b0, b1, b2,
                                                          Qt, Kt, Vt, scale);
    attn_kernel<<<dim3(8, 128), 256, 0, stream>>>(Qt, Kt, Vt, out);
}

// Round 10
// 233.249 us; speedup vs baseline: 1.2626x; 1.2626x over previous
//
#include <hip/hip_runtime.h>

// Problem constants
#define B_SZ 16
#define CIN  512
#define LIN  1024
#define LP   1022      // L - K + 1
#define HEADS 8
#define DH    64

typedef __attribute__((ext_vector_type(8))) short bf16x8;
typedef __attribute__((ext_vector_type(4))) float f32x4;
typedef __attribute__((ext_vector_type(16))) float f32x16;

__device__ inline unsigned short f2bf(float f) {
    union { float f; unsigned int u; } c; c.f = f;
    unsigned int r = c.u + 0x7FFF + ((c.u >> 16) & 1);   // RNE
    return (unsigned short)(r >> 16);
}

// async global->LDS DMA, 16B per lane, LDS dst = wave-uniform base + lane*16
__device__ __forceinline__ void gl_lds16(const unsigned short* g, unsigned short* l) {
    __builtin_amdgcn_global_load_lds((const __attribute__((address_space(1))) void*)g,
                                     (__attribute__((address_space(3))) void*)l, 16, 0, 0);
}

// XOR swizzle on 16B granules: involution, preserves 8-granule blocks,
// spreads 16 consecutive rows across all 8 bank groups (2-way = free).
#define SWZ(G) ((G) ^ (((G) >> 3) & 7))

// ---------------------------------------------------------------------------
// xb cvt: x fp32 [b][512 i][1024 l] -> xb bf16 [b][1024 l][512 i]
// ---------------------------------------------------------------------------
__global__ __launch_bounds__(256) void xb_cvt_kernel(const float* __restrict__ x,
                                                     unsigned short* __restrict__ xb) {
    __shared__ float sm[64][68];
    const int t  = threadIdx.x;
    const int l0 = blockIdx.x * 64;
    const int i0 = blockIdx.y * 64;
    const int b  = blockIdx.z;
    const float* S = x + ((size_t)b * CIN + i0) * LIN;

    #pragma unroll
    for (int rr = 0; rr < 4; rr++) {
        int idx = rr * 1024 + t * 4;
        int ii = idx >> 6, lj = idx & 63;
        *(float4*)&sm[ii][lj] = *(const float4*)(S + (size_t)ii * LIN + l0 + lj);
    }
    __syncthreads();

    #pragma unroll
    for (int rr = 0; rr < 4; rr++) {
        int idx = rr * 1024 + t * 4;
        int l = idx >> 6, dj = idx & 63;
        ushort4 h;
        h.x = f2bf(sm[dj + 0][l]);
        h.y = f2bf(sm[dj + 1][l]);
        h.z = f2bf(sm[dj + 2][l]);
        h.w = f2bf(sm[dj + 3][l]);
        *(ushort4*)(xb + ((size_t)b * 1024 + l0 + l) * 512 + i0 + dj) = h;
    }
}

// ---------------------------------------------------------------------------
// wb cvt: w_c[o][i][kk] fp32 -> wb bf16 [kk][O=c*512+o][i]
// ---------------------------------------------------------------------------
__global__ __launch_bounds__(256) void wb_cvt_kernel(const float* __restrict__ w0,
                                                     const float* __restrict__ w1,
                                                     const float* __restrict__ w2,
                                                     unsigned short* __restrict__ wb) {
    const int kk = blockIdx.y;
    int flat = blockIdx.x * 256 + threadIdx.x;
    int i  = flat & 511;
    int oG = flat >> 9;
    int c  = oG >> 9, o = oG & 511;
    const float* w = (c == 0) ? w0 : (c == 1) ? w1 : w2;
    wb[(size_t)kk * 786432 + flat] = f2bf(w[o * 1536 + i * 3 + kk]);
}

// ---------------------------------------------------------------------------
// Fused 3-conv bf16 MFMA GEMM with global_load_lds staging + XOR-swizzled LDS.
// Round-0 structure (median 93 us, the m97 plateau). Frozen: 8-phase ports
// (r1/r2) and DS-read dedup (r8) all failed to move it.
// ---------------------------------------------------------------------------
__global__ __launch_bounds__(256) void conv_mfma_kernel(
        const unsigned short* __restrict__ xb,   // [16][1024][512]
        const unsigned short* __restrict__ wb,   // [3][1536][512]
        const float* __restrict__ b0, const float* __restrict__ b1,
        const float* __restrict__ b2,
        unsigned short* __restrict__ Qt, unsigned short* __restrict__ Kt,
        unsigned short* __restrict__ Vt, float qscale) {
    __shared__ unsigned short smem[16896];       // staging 16512 sh | vt 16896 sh
    unsigned short* xs = smem;                   // [132][32]
    unsigned short* ws = smem + 4224;            // [384][32]

    const int t    = threadIdx.x;
    const int wave = t >> 6;
    const int lane = t & 63;
    const int col  = lane & 15;
    const int quad = lane >> 4;
    const int wh   = wave >> 1;                  // o half
    const int wn   = wave & 1;                   // l half
    const int l0   = blockIdx.x * 128;
    const int o0   = blockIdx.y * 128;
    const int b    = blockIdx.z;

    f32x4 acc[4][4];
    #pragma unroll
    for (int i = 0; i < 4; i++)
        #pragma unroll
        for (int j = 0; j < 4; j++) acc[i][j] = (f32x4){0.f, 0.f, 0.f, 0.f};

    const unsigned short* xrow = xb + (size_t)b * 1024 * 512;

    for (int ic = 0; ic < 512; ic += 32) {
        __syncthreads();   // previous chunk's compute done before overwrite

        // ---- W DMA: 24 instrs (16 rows each), this wave does 6 ----
        #pragma unroll
        for (int j = 0; j < 6; j++) {
            int instr = wave * 6 + j;
            int Gg = SWZ(instr * 64 + lane);
            int p = Gg >> 2, q = Gg & 3;
            int kk = p >> 7, orow = p & 127;
            gl_lds16(wb + ((size_t)(kk * 1536 + o0 + orow)) * 512 + ic + q * 8,
                     ws + instr * 512);
        }
        // ---- X DMA: 8 instrs for rows 0..127, this wave does 2 ----
        #pragma unroll
        for (int j = 0; j < 2; j++) {
            int instr = wave * 2 + j;
            int Gg = SWZ(instr * 64 + lane);
            int p = Gg >> 2, q = Gg & 3;
            gl_lds16(xrow + (size_t)(l0 + p) * 512 + ic + q * 8,
                     xs + instr * 512);
        }
        // ---- halo rows 128,129 (checked, zero-fill OOB) ----
        if (t < 8) {
            int row = 128 + (t >> 2), sg = t & 3;
            int gl = l0 + row;
            bf16x8 v = (bf16x8){0, 0, 0, 0, 0, 0, 0, 0};
            if (gl < 1024) v = *(const bf16x8*)(xrow + (size_t)gl * 512 + ic + sg * 8);
            *(bf16x8*)&xs[SWZ(512 + t) * 8] = v;
        }
        __syncthreads();   // drains vmcnt (DMA) + lgkmcnt (halo)

        #pragma unroll
        for (int kk = 0; kk < 3; kk++) {
            bf16x8 af[4], bfr[4];
            #pragma unroll
            for (int ms = 0; ms < 4; ms++) {
                int G = ((kk * 128 + wh * 64 + ms * 16 + col) << 2) | quad;
                af[ms] = *(const bf16x8*)&ws[SWZ(G) * 8];
            }
            #pragma unroll
            for (int ns = 0; ns < 4; ns++) {
                int G = ((wn * 64 + ns * 16 + col + kk) << 2) | quad;
                bfr[ns] = *(const bf16x8*)&xs[SWZ(G) * 8];
            }
            #pragma unroll
            for (int ms = 0; ms < 4; ms++)
                #pragma unroll
                for (int ns = 0; ns < 4; ns++)
                    acc[ms][ns] = __builtin_amdgcn_mfma_f32_16x16x32_bf16(af[ms], bfr[ns], acc[ms][ns], 0, 0, 0);
        }
    }

    const int c = blockIdx.y >> 2;               // which conv (uniform per block)

    if (c < 2) {
        // ---- Q/K epilogue: direct bf16 stores to [bh][l][d] ----
        unsigned short* dst = (c == 0) ? Qt : Kt;
        const float* bias   = (c == 0) ? b0 : b1;
        const float sc      = (c == 0) ? qscale : 1.0f;
        const int h = (((o0 & 511) + wh * 64) >> 6) & 7;
        unsigned short* base = dst + (size_t)(b * 8 + h) * 65536;
        #pragma unroll
        for (int ms = 0; ms < 4; ms++) {
            int ob = (o0 & 511) + wh * 64 + ms * 16 + quad * 4;
            float bv[4];
            #pragma unroll
            for (int r = 0; r < 4; r++) bv[r] = bias[ob + r];
            int d0 = ms * 16 + quad * 4;
            #pragma unroll
            for (int ns = 0; ns < 4; ns++) {
                int l = l0 + wn * 64 + ns * 16 + col;
                ushort4 hv;
                hv.x = f2bf((acc[ms][ns][0] + bv[0]) * sc);
                hv.y = f2bf((acc[ms][ns][1] + bv[1]) * sc);
                hv.z = f2bf((acc[ms][ns][2] + bv[2]) * sc);
                hv.w = f2bf((acc[ms][ns][3] + bv[3]) * sc);
                *(ushort4*)(base + (size_t)l * 64 + d0) = hv;
            }
        }
    } else {
        // ---- V epilogue: LDS transpose then coalesced rows to [bh][d][1024] ----
        __syncthreads();
        unsigned short* vt = smem;               // [128][132]
        #pragma unroll
        for (int ms = 0; ms < 4; ms++) {
            int ob = (o0 & 511) + wh * 64 + ms * 16 + quad * 4;
            #pragma unroll
            for (int ns = 0; ns < 4; ns++) {
                int lc = wn * 64 + ns * 16 + col;
                #pragma unroll
                for (int r = 0; r < 4; r++)
                    vt[(wh * 64 + ms * 16 + quad * 4 + r) * 132 + lc] =
                        f2bf(acc[ms][ns][r] + b2[ob + r]);
            }
        }
        __syncthreads();
        #pragma unroll
        for (int it = 0; it < 8; it++) {
            int flat = it * 2048 + t * 8;
            int row = flat >> 7, colx = flat & 127;
            bf16x8 v = *(const bf16x8*)&vt[row * 132 + colx];
            int og = (o0 & 511) + row;
            int h = og >> 6, d = og & 63;
            *(bf16x8*)(Vt + ((size_t)(b * 8 + h) * 64 + d) * 1024 + l0 + colx) = v;
        }
    }
}

// ---------------------------------------------------------------------------
// Flash attention, 32x32x16 MFMA, no-max softmax (p = 2^s, log2e in Q).
// Swapped QK (A=K, B=Q); P fully in-register (round-6 structure, verified).
//
// Round 10: LDS staging RESTORED (r9 proved it's worth ~60us: direct-load =
// latency-serialized, 131us). One change vs round 6: TRIPLE-buffered K/V with
// counted vmcnt — issue tile kt+2 during kt, boundary waits vmcnt(4) (kt+1
// landed, kt+2 in flight), vmcnt(0) only at kt=14. DMA gets ~2 tiles of
// latency slack instead of ~1 tile's compute (T4, per-wave count = 4 loads).
// Pack exchange: v_permlane32_swap_b32 (HW-verified in r9, absmax equal).
// LDS 48KB -> 3 blocks/CU.
// ---------------------------------------------------------------------------
__global__ __launch_bounds__(256, 3) void attn_kernel(
        const unsigned short* __restrict__ Qt,
        const unsigned short* __restrict__ Kt,
        const unsigned short* __restrict__ Vt,
        float* __restrict__ out) {
    __shared__ unsigned short asmem[24576];      // 3 x [K 4096 | V 4096]

    const int t    = threadIdx.x;
    const int wave = t >> 6;
    const int lane = t & 63;
    const int col5 = lane & 31;
    const int hi   = lane >> 5;

    // XCD-grouping swizzle (bijective over the 1024-block grid): each XCD
    // gets 16 bh x 8 qb, so K/V panels are reused within one L2.
    const int lin = blockIdx.y * 8 + blockIdx.x; // 0..1023
    const int xcd = lin & 7;
    const int idx = lin >> 3;                    // 0..127
    const int qb  = idx >> 4;                    // 0..7
    const int bh  = xcd * 16 + (idx & 15);       // 0..127

    const size_t base64 = (size_t)bh * 65536;
    const int q0 = qb * 128 + wave * 32;

    // Q B-frags: bq[s] = Q[q0+col5][s*16 + hi*8 + e]
    bf16x8 bq[4];
    {
        const unsigned short* qrow = Qt + base64 + (size_t)(q0 + col5) * 64 + hi * 8;
        #pragma unroll
        for (int s = 0; s < 4; s++) bq[s] = *(const bf16x8*)(qrow + s * 16);
    }

    f32x16 o0, o1;                               // O[d=col-rows], d-blocks 0/1
    #pragma unroll
    for (int i = 0; i < 16; i++) { o0[i] = 0.f; o1[i] = 0.f; }
    float osum = 0.f;

    const unsigned short* kg0 = Kt + base64;
    const unsigned short* vg  = Vt + base64;

    // ---- stage helper (4 loads/wave/tile, K+V interleaved) ----
    auto stage = [&](int tile, unsigned short* buf) {
        const unsigned short* kg = kg0 + (size_t)tile * 4096;
        #pragma unroll
        for (int j = 0; j < 2; j++) {
            int i = wave + j * 4;                // instr 0..7
            int G = SWZ(i * 64 + lane);
            gl_lds16(kg + (size_t)G * 8, buf + i * 512);
            int p = G >> 3, q = G & 7;
            gl_lds16(vg + (size_t)p * 1024 + tile * 64 + q * 8,
                     buf + 4096 + i * 512);
        }
    };

    // ---- prologue: stage tiles 0,1 -> buf0,buf1 ----
    stage(0, asmem);
    stage(1, asmem + 8192);
    asm volatile("s_waitcnt vmcnt(4)" ::: "memory");   // tile0 landed; tile1 in flight
    __builtin_amdgcn_s_barrier();
    asm volatile("" ::: "memory");

    int cur = 0;                                 // buffer index of tile kt
    for (int kt = 0; kt < 16; kt++) {
        // buf[(kt+2)%3] == buf[(kt-1)%3]: all waves finished reading tile
        // kt-1 (they passed the end-of-tile-(kt-1) barrier) -> safe to DMA.
        int nxt = cur + 2; if (nxt >= 3) nxt -= 3;
        if (kt < 14) stage(kt + 2, asmem + nxt * 8192);

        const unsigned short* Ksb = asmem + cur * 8192;
        const unsigned short* Vsb = Ksb + 4096;

        #pragma unroll
        for (int kb = 0; kb < 2; kb++) {
            // ---- frag reads: K rows kb*32+col5, V rows db*32+col5 ----
            bf16x8 ak[4];
            #pragma unroll
            for (int s = 0; s < 4; s++)
                ak[s] = *(const bf16x8*)&Ksb[SWZ((kb * 32 + col5) * 8 + s * 2 + hi) * 8];
            bf16x8 av[2][2];
            #pragma unroll
            for (int db = 0; db < 2; db++)
                #pragma unroll
                for (int s = 0; s < 2; s++)
                    av[db][s] = *(const bf16x8*)&Vsb[SWZ((db * 32 + col5) * 8 + kb * 4 + s * 2 + hi) * 8];

            // ---- S^T = K Q^T over d (4 chained K=16 steps) ----
            f32x16 p;
            #pragma unroll
            for (int i = 0; i < 16; i++) p[i] = 0.f;
            __builtin_amdgcn_s_setprio(1);
            #pragma unroll
            for (int s = 0; s < 4; s++)
                p = __builtin_amdgcn_mfma_f32_32x32x16_bf16(ak[s], bq[s], p, 0, 0, 0);
            __builtin_amdgcn_s_setprio(0);

            // ---- p = 2^s in-register; rowsum locally ----
            float e[16];
            #pragma unroll
            for (int r = 0; r < 16; r++) e[r] = exp2f(p[r]);
            if (kt == 15 && kb == 1 && hi == 1) { e[14] = 0.f; e[15] = 0.f; }  // keys 1022,1023
            #pragma unroll
            for (int r = 0; r < 16; r++) osum += e[r];

            // ---- build PV B-frags: cvt_pk + permlane32_swap cross-half ----
            bf16x8 bp[2];
            #pragma unroll
            for (int s = 0; s < 2; s++) {
                unsigned int a, b_, c, d;
                asm("v_cvt_pk_bf16_f32 %0, %1, %2" : "=v"(a)  : "v"(e[s*8+0]), "v"(e[s*8+1]));
                asm("v_cvt_pk_bf16_f32 %0, %1, %2" : "=v"(b_) : "v"(e[s*8+2]), "v"(e[s*8+3]));
                asm("v_cvt_pk_bf16_f32 %0, %1, %2" : "=v"(c)  : "v"(e[s*8+4]), "v"(e[s*8+5]));
                asm("v_cvt_pk_bf16_f32 %0, %1, %2" : "=v"(d)  : "v"(e[s*8+6]), "v"(e[s*8+7]));
                // after swap: a={a.lo,c.lo} (word0), c={a.hi,c.hi} (word2)
                asm("v_permlane32_swap_b32 %0, %1" : "+v"(a), "+v"(c));
                asm("v_permlane32_swap_b32 %0, %1" : "+v"(b_), "+v"(d));
                union { unsigned int u[4]; bf16x8 v; } pk;
                pk.u[0] = a;
                pk.u[1] = b_;
                pk.u[2] = c;
                pk.u[3] = d;
                bp[s] = pk.v;
            }

            // ---- O += V P ----
            __builtin_amdgcn_s_setprio(1);
            #pragma unroll
            for (int s = 0; s < 2; s++) {
                o0 = __builtin_amdgcn_mfma_f32_32x32x16_bf16(av[0][s], bp[s], o0, 0, 0, 0);
                o1 = __builtin_amdgcn_mfma_f32_32x32x16_bf16(av[1][s], bp[s], o1, 0, 0, 0);
            }
            __builtin_amdgcn_s_setprio(0);
        }

        // ---- boundary: counted wait (kt+1 landed; kt+2's 4 stay in flight) ----
        if (kt < 14)       asm volatile("s_waitcnt vmcnt(4)" ::: "memory");
        else if (kt == 14) asm volatile("s_waitcnt vmcnt(0)" ::: "memory");
        __builtin_amdgcn_s_barrier();
        asm volatile("" ::: "memory");
        cur = cur + 1; if (cur >= 3) cur -= 3;
    }

    // ---- epilogue: rowsum cross-half combine, divide, store ----
    float osum_t = osum + __shfl_xor(osum, 32);
    float inv = 1.0f / osum_t;
    int q = q0 + col5;
    if (q < LP) {
        #pragma unroll
        for (int r = 0; r < 16; r++) {
            int d0 = (r & 3) + 8 * (r >> 2) + 4 * hi;
            out[((size_t)(bh * 64 + d0)) * LP + q]      = o0[r] * inv;
            out[((size_t)(bh * 64 + d0 + 32)) * LP + q] = o1[r] * inv;
        }
    }
}

// ---------------------------------------------------------------------------
extern "C" void kernel_launch(void* const* d_in, const int* in_sizes, int n_in,
                              void* d_out, int out_size, void* d_ws, size_t ws_size,
                              hipStream_t stream) {
    const float* x  = (const float*)d_in[0];
    const float* w0 = (const float*)d_in[1];
    const float* b0 = (const float*)d_in[2];
    const float* w1 = (const float*)d_in[3];
    const float* b1 = (const float*)d_in[4];
    const float* w2 = (const float*)d_in[5];
    const float* b2 = (const float*)d_in[6];
    float* out = (float*)d_out;

    // workspace (ushort units): xb 8388608 | wb 2359296 | Qt/Kt/Vt 8388608 each
    unsigned short* xbp = (unsigned short*)d_ws;
    unsigned short* wbp = xbp + 8388608;
    unsigned short* Qt  = wbp + 2359296;
    unsigned short* Kt  = Qt + 8388608;
    unsigned short* Vt  = Kt + 8388608;

    // 1/sqrt(512) * log2(e): softmax computed as 2^s
    const float scale = 0.06375870864f;

    xb_cvt_kernel<<<dim3(16, 8, 16), 256, 0, stream>>>(x, xbp);
    wb_cvt_kernel<<<dim3(3072, 3), 256, 0, stream>>>(w0, w1, w2, wbp);
    conv_mfma_kernel<<<dim3(8, 12, 16), 256, 0, stream>>>(xbp, wbp, b0, b1, b2,
                                                          Qt, Kt, Vt, scale);
    attn_kernel<<<dim3(8, 128), 256, 0, stream>>>(Qt, Kt, Vt, out);
}